// Round 4
// baseline (217.549 us; speedup 1.0000x reference)
//
#include <hip/hip_runtime.h>

// Problem constants (match reference)
#define NN      4096   // N and N_NEXT
#define NU      2048   // NUM_UNSTABLE
#define PROWS   8192   // P_ROWS

// d_ws layout (floats):
//   [0,     4096) : sV       — sV[m] = sum_k V_next[k] * W_next[m][k]  (ROW dot!)
//   [4096,  6144) : pP       = pi_i @ P_i      (column outputs)
//   [6144,  8192) : pPhat    = pi_i @ P_hat_i  (column outputs)
//   [8192, 12288) : rank (int) — exclusive count of unstable neurons with index < n

// ---------------------------------------------------------------------------
// Kernel 1: zero the accumulator region + compute unstable ranks (block scan).
// One block, 1024 threads, 4 neurons/thread.
// ---------------------------------------------------------------------------
__global__ __launch_bounds__(1024)
void rank_and_zero(const float* __restrict__ L, const float* __restrict__ U,
                   float* __restrict__ ws) {
  const int tid = threadIdx.x;

  // zero 8192 floats (accumulators) — 2 float4 per thread
  float4 z = make_float4(0.f, 0.f, 0.f, 0.f);
  reinterpret_cast<float4*>(ws)[tid * 2 + 0] = z;
  reinterpret_cast<float4*>(ws)[tid * 2 + 1] = z;

  int* rank = reinterpret_cast<int*>(ws + 8192);

  const int base = tid * 4;
  int m[4];
  int cnt = 0;
#pragma unroll
  for (int j = 0; j < 4; ++j) {
    const float l = L[base + j], u = U[base + j];
    m[j] = (l < 0.f && u > 0.f) ? 1 : 0;
    cnt += m[j];
  }

  // inclusive scan of per-thread counts within each 64-lane wave
  const int lane = tid & 63;
  const int wave = tid >> 6;
  int scan = cnt;
#pragma unroll
  for (int off = 1; off < 64; off <<= 1) {
    int nb = __shfl_up(scan, off, 64);
    if (lane >= off) scan += nb;
  }

  __shared__ int wave_sums[16];
  if (lane == 63) wave_sums[wave] = scan;
  __syncthreads();

  // scan the 16 wave totals with the first 16 lanes of wave 0
  if (wave == 0 && lane < 16) {
    int s = wave_sums[lane];
#pragma unroll
    for (int off = 1; off < 16; off <<= 1) {
      int nb = __shfl_up(s, off, 64);
      if (lane >= off) s += nb;
    }
    wave_sums[lane] = s;
  }
  __syncthreads();

  const int wave_off = (wave > 0) ? wave_sums[wave - 1] : 0;
  int exc = wave_off + scan - cnt;  // exclusive prefix for this thread's 4 elems
#pragma unroll
  for (int j = 0; j < 4; ++j) {
    rank[base + j] = exc;
    exc += m[j];
  }
}

// ---------------------------------------------------------------------------
// Kernel 2: fused mat-vec work.
//   blocks [0, 1024):    sV[row] = dot(V_next, W_next[row, :])  — one WAVE per
//                        row; lanes stride the row with float4, coalesced;
//                        shfl_xor wave reduction; lane 0 stores. Rows with
//                        U[row] <= 0 are skipped (sV unused for deact).
//   blocks [1024, 1536): pP / pPhat column-dots: out[c] = sum_r pi[r]*M[r][c];
//                        each block does 64 rows x 1024 cols, atomicAdd 4
//                        partials per thread.
// ---------------------------------------------------------------------------
__global__ __launch_bounds__(256)
void fused_matvec(const float* __restrict__ V_next, const float* __restrict__ W,
                  const float* __restrict__ pi, const float* __restrict__ P,
                  const float* __restrict__ Phat, const float* __restrict__ U,
                  float* __restrict__ ws) {
  const int bid = blockIdx.x;
  const int tid = threadIdx.x;

  if (bid < 1024) {
    // ---- seg 0: row dot ----
    const int wave = tid >> 6;
    const int lane = tid & 63;
    const int row  = bid * 4 + wave;
    if (U[row] <= 0.f) return;  // stably deactivated: sV never consumed

    const float4* Wr = reinterpret_cast<const float4*>(W + (size_t)row * NN);
    const float4* V4 = reinterpret_cast<const float4*>(V_next);

    float acc = 0.f;
#pragma unroll
    for (int it = 0; it < 16; ++it) {
      const float4 w4 = Wr[it * 64 + lane];
      const float4 v4 = V4[it * 64 + lane];
      acc = fmaf(w4.x, v4.x, acc);
      acc = fmaf(w4.y, v4.y, acc);
      acc = fmaf(w4.z, v4.z, acc);
      acc = fmaf(w4.w, v4.w, acc);
    }
#pragma unroll
    for (int off = 32; off > 0; off >>= 1) acc += __shfl_xor(acc, off, 64);
    if (lane == 0) ws[row] = acc;
  } else {
    // ---- segs 1/2: column dots with atomic accumulation ----
    const int b   = bid - 1024;
    const int seg = b >> 8;      // 0 -> P, 1 -> Phat
    const int loc = b & 255;

    const float* mat = seg ? Phat : P;
    float* out = ws + (seg ? 6144 : 4096);
    const int colTile = loc & 1;
    const int chunk   = loc >> 1;

    const int col  = colTile * 1024 + tid * 4;
    const int row0 = chunk * 64;

    float4 acc = make_float4(0.f, 0.f, 0.f, 0.f);
    const float* mp = mat + (size_t)row0 * NU + col;
#pragma unroll 4
    for (int r = 0; r < 64; ++r) {
      const float v = pi[row0 + r];          // wave-uniform scalar load
      const float4 m = *reinterpret_cast<const float4*>(mp);
      acc.x = fmaf(v, m.x, acc.x);
      acc.y = fmaf(v, m.y, acc.y);
      acc.z = fmaf(v, m.z, acc.z);
      acc.w = fmaf(v, m.w, acc.w);
      mp += NU;
    }
    atomicAdd(out + col + 0, acc.x);
    atomicAdd(out + col + 1, acc.y);
    atomicAdd(out + col + 2, acc.z);
    atomicAdd(out + col + 3, acc.w);
  }
}

// ---------------------------------------------------------------------------
// Kernel 3: epilogue — masks + unstable formula.
// Reference override order: stably_deact (-C) overrides stably_act (sV - C).
// ---------------------------------------------------------------------------
__global__ __launch_bounds__(256)
void epilogue(const float* __restrict__ ws, const float* __restrict__ C,
              const float* __restrict__ L, const float* __restrict__ U,
              const float* __restrict__ alpha, float* __restrict__ out) {
  const int n = blockIdx.x * 256 + threadIdx.x;
  if (n >= NN) return;
  const float l = L[n], u = U[n], c = C[n];
  const int* rank = reinterpret_cast<const int*>(ws + 8192);

  float res;
  if (u <= 0.f) {
    res = -c;                       // stably deactivated
  } else if (l >= 0.f) {
    res = ws[n] - c;                // stably activated: sV - C
  } else {
    // unstable: l < 0 < u
    const int uu = rank[n];
    const float vhat = ws[n] - ws[6144 + uu];
    const float pos = fmaxf(vhat, 0.f);
    const float neg = fmaxf(-vhat, 0.f);
    res = pos * u / (u - l) - c - alpha[uu] * neg - ws[4096 + uu];
  }
  out[n] = res;
}

extern "C" void kernel_launch(void* const* d_in, const int* in_sizes, int n_in,
                              void* d_out, int out_size, void* d_ws, size_t ws_size,
                              hipStream_t stream) {
  const float* V_next  = (const float*)d_in[0];
  const float* W_next  = (const float*)d_in[1];
  const float* C_i     = (const float*)d_in[2];
  const float* L_i     = (const float*)d_in[3];
  const float* U_i     = (const float*)d_in[4];
  const float* P_i     = (const float*)d_in[5];
  const float* P_hat_i = (const float*)d_in[6];
  const float* pi_i    = (const float*)d_in[7];
  const float* alpha_i = (const float*)d_in[8];
  float* out = (float*)d_out;
  float* ws  = (float*)d_ws;

  rank_and_zero<<<1, 1024, 0, stream>>>(L_i, U_i, ws);
  fused_matvec<<<1536, 256, 0, stream>>>(V_next, W_next, pi_i, P_i, P_hat_i, U_i, ws);
  epilogue<<<NN / 256, 256, 0, stream>>>(ws, C_i, L_i, U_i, alpha_i, out);
}